// Round 16
// baseline (2730.805 us; speedup 1.0000x reference)
//
#include <hip/hip_runtime.h>

__device__ __forceinline__ float lrelu(float v){ return v >= 0.f ? v : 0.1f*v; }

// R16: fuse2 staging via __builtin_amdgcn_global_load_lds (width 16) + counted vmcnt —
// removes VMEM->VGPR->ds_write round trip. Slot m lands at LDS byte m*16 (contiguous).
__device__ __forceinline__ void gl16(const float* g, float* l){
  __builtin_amdgcn_global_load_lds((const __attribute__((address_space(1))) unsigned int*)g,
                                   (__attribute__((address_space(3))) unsigned int*)l,
                                   16, 0, 0);
}

// ---------------- weight repack: [4][64co][64ci][9] -> [4][64ci][64co][9], 3 tensors
__global__ __launch_bounds__(256) void k_wrep(const float* __restrict__ wspa, const float* __restrict__ wang,
                                              const float* __restrict__ wf2, float* __restrict__ outp){
  int id = blockIdx.x*256 + threadIdx.x;       // < 442368
  int t = id / 147456, r = id - t*147456;
  int i = r / 36864,  e = r - i*36864;
  int ci = e / 576,   r3 = e - ci*576;
  int co = r3 / 9,    j = r3 - co*9;
  const float* src = (t==0 ? wspa : (t==1 ? wang : wf2));
  outp[id] = src[(size_t)i*36864 + co*576 + ci*9 + j];
}

// ---------------- spa: per-view 3x3 conv (1-wave blocks, wave-sync, R15) ---
__global__ __launch_bounds__(64) void k_spa(const float* __restrict__ buf1, const float* __restrict__ w,
                                            float* __restrict__ out){
  const int P = blockIdx.x;
  const int xcd = P & 7, within = P >> 3;
  const int wv = within & 3, cog = (within >> 2) & 7, tsel = within >> 5;  // tsel 0..24
  const int tg = xcd*25 + tsel;                // 0..199
  const int b = tg / 50, r2 = tg % 50;
  const int view = r2 >> 1, half = r2 & 1;
  const int bi = view / 5, bj = view % 5;
  const int th0 = half*16;
  const int lane = threadIdx.x;
  __shared__ float wl[2][240];      // 6 rows x 40 (data cols 4..35, zeros 3/36), 2 bufs
  for (int i=lane; i<480; i+=64) ((float*)wl)[i] = 0.f;
  float acc[2][8];
  #pragma unroll
  for (int k=0;k<2;k++)
    #pragma unroll
    for (int c2=0;c2<8;c2++) acc[k][c2]=0.f;
  const float* src = buf1 + (size_t)b*1638400 + bi*32*160 + bj*32;
  const int srow = lane >> 3, sq = (lane & 7)*4;
  const int vr = th0 + 4*wv - 1 + srow;
  const bool rowok = (lane < 48) && ((unsigned)vr < 32u);
  const int dst = srow*40 + 4 + sq;
  if (rowok)
    *(float4*)&wl[0][dst] = *(const float4*)(src + vr*160 + sq);
  const int lrl = (lane >> 5) & 1, c = lane & 31;
  for (int ci=0; ci<64; ci++){
    float4 nx;
    const bool ld = rowok && (ci < 63);
    if (ld) nx = *(const float4*)(src + (size_t)(ci+1)*25600 + vr*160 + sq);
    const float* Pb = wl[ci & 1];
    float g[4][3];
    {
      const float* pp = &Pb[(2*lrl)*40 + c + 3];
      g[0][0]=pp[0];   g[0][1]=pp[1];   g[0][2]=pp[2];
      g[1][0]=pp[40];  g[1][1]=pp[41];  g[1][2]=pp[42];
      g[2][0]=pp[80];  g[2][1]=pp[81];  g[2][2]=pp[82];
      g[3][0]=pp[120]; g[3][1]=pp[121]; g[3][2]=pp[122];
    }
    const float* wrow = w + ci*576 + cog*72;   // repacked: 72 contiguous dwords
    #pragma unroll
    for (int co=0;co<8;co++){
      const float* wp = wrow + co*9;
      float w0=wp[0],w1=wp[1],w2=wp[2],w3=wp[3],w4=wp[4],w5=wp[5],w6=wp[6],w7=wp[7],w8=wp[8];
      acc[0][co] += g[0][0]*w0+g[0][1]*w1+g[0][2]*w2+g[1][0]*w3+g[1][1]*w4
                  + g[1][2]*w5+g[2][0]*w6+g[2][1]*w7+g[2][2]*w8;
      acc[1][co] += g[1][0]*w0+g[1][1]*w1+g[1][2]*w2+g[2][0]*w3+g[2][1]*w4
                  + g[2][2]*w5+g[3][0]*w6+g[3][1]*w7+g[3][2]*w8;
    }
    if (ld) *(float4*)&wl[(ci+1)&1][dst] = nx;
  }
  #pragma unroll
  for (int k=0;k<2;k++){
    int si = th0 + 4*wv + 2*lrl + k;
    int h = si*5 + bi, wq = c*5 + bj;
    #pragma unroll
    for (int co=0;co<8;co++){
      int ch = b*64 + cog*8 + co;
      out[(size_t)ch*25600 + h*160 + wq] = lrelu(acc[k][co]);
    }
  }
}

// ---------------- ang: per-macropixel (5x5) 3x3 conv (unchanged R13) ------
__global__ __launch_bounds__(320) void k_ang(const float* __restrict__ bufA, const float* __restrict__ w,
                                             float* __restrict__ out){
  const int P = blockIdx.x;
  const int within = P >> 3, cog = within & 15, tsel = within >> 4;
  const int tg = (P & 7)*8 + tsel;             // 0..63
  const int b = tg >> 4, mip = tg & 15;
  const int tid = threadIdx.x;
  __shared__ float lds[2][2296];
  for (int i=tid; i<2*2296; i+=320) ((float*)lds)[i] = 0.f;

  const int u = tid >> 6, mi_l = (tid >> 5) & 1, mp = tid & 31;
  int ro[3];
  #pragma unroll
  for (int du=0; du<3; du++)
    ro[du] = mi_l*1148 + (u+du)*164 + mp*5;
  const bool st1 = tid < 80;
  const int rr0 = tid/40,       q0 = tid%40;
  const int rr1 = (tid+320)/40, q1 = (tid+320)%40;
  const int dst0 = (rr0/5)*1148 + (1 + rr0%5)*164 + q0*4;
  const int dst1 = (rr1/5)*1148 + (1 + rr1%5)*164 + q1*4;
  const float* src = bufA + (size_t)b*1638400 + (size_t)(mip*10)*160;

  float acc[4][5];
  #pragma unroll
  for (int co=0;co<4;co++)
    #pragma unroll
    for (int v=0;v<5;v++) acc[co][v]=0.f;

  __syncthreads();
  {
    *(float4*)&lds[0][dst0] = *(const float4*)(src + rr0*160 + q0*4);
    if (st1)
      *(float4*)&lds[0][dst1] = *(const float4*)(src + rr1*160 + q1*4);
  }
  __syncthreads();
  for (int ci=0; ci<64; ci++){
    float4 n0, n1;
    if (ci < 63){
      n0 = *(const float4*)(src + (size_t)(ci+1)*25600 + rr0*160 + q0*4);
      if (st1) n1 = *(const float4*)(src + (size_t)(ci+1)*25600 + rr1*160 + q1*4);
    }
    const float* Pb = lds[ci & 1];
    float c[3][5];
    #pragma unroll
    for (int du=0;du<3;du++){
      const float* rp = &Pb[ro[du]];
      c[du][0]=rp[0]; c[du][1]=rp[1]; c[du][2]=rp[2]; c[du][3]=rp[3]; c[du][4]=rp[4];
    }
    const float* wrow = w + ci*576 + cog*36;
    #pragma unroll
    for (int co=0;co<4;co++){
      const float* wp = wrow + co*9;
      float w0=wp[0],w1=wp[1],w2=wp[2],w3=wp[3],w4=wp[4],w5=wp[5],w6=wp[6],w7=wp[7],w8=wp[8];
      acc[co][0] += c[0][0]*w1 + c[0][1]*w2
                  + c[1][0]*w4 + c[1][1]*w5
                  + c[2][0]*w7 + c[2][1]*w8;
      acc[co][1] += c[0][0]*w0 + c[0][1]*w1 + c[0][2]*w2
                  + c[1][0]*w3 + c[1][1]*w4 + c[1][2]*w5
                  + c[2][0]*w6 + c[2][1]*w7 + c[2][2]*w8;
      acc[co][2] += c[0][1]*w0 + c[0][2]*w1 + c[0][3]*w2
                  + c[1][1]*w3 + c[1][2]*w4 + c[1][3]*w5
                  + c[2][1]*w6 + c[2][2]*w7 + c[2][3]*w8;
      acc[co][3] += c[0][2]*w0 + c[0][3]*w1 + c[0][4]*w2
                  + c[1][2]*w3 + c[1][3]*w4 + c[1][4]*w5
                  + c[2][2]*w6 + c[2][3]*w7 + c[2][4]*w8;
      acc[co][4] += c[0][3]*w0 + c[0][4]*w1
                  + c[1][3]*w3 + c[1][4]*w4
                  + c[2][3]*w6 + c[2][4]*w7;
    }
    if (ci < 63){
      float* Q = lds[(ci+1)&1];
      *(float4*)&Q[dst0] = n0;
      if (st1) *(float4*)&Q[dst1] = n1;
    }
    __syncthreads();
  }
  const int h = (mip*2 + mi_l)*5 + u;
  const int wc0 = mp*5;
  #pragma unroll
  for (int co=0;co<4;co++){
    int ch = b*64 + cog*4 + co;
    float* op = out + (size_t)ch*25600 + (size_t)h*160 + wc0;
    op[0]=lrelu(acc[co][0]); op[1]=lrelu(acc[co][1]); op[2]=lrelu(acc[co][2]);
    op[3]=lrelu(acc[co][3]); op[4]=lrelu(acc[co][4]);
  }
}

// ---------------- fused EPI (unchanged R13) --------------------------------
__global__ __launch_bounds__(320) void k_epi(const float* __restrict__ bufA, const float* __restrict__ we1,
                                             const float* __restrict__ we2, float* __restrict__ out){
  const int bb = blockIdx.x >> 1, half = blockIdx.x & 1;
  const int b = bb / 160, hw = bb % 160;
  const int tid = threadIdx.x;
  __shared__ float rowp[64*96];
  __shared__ float y1s[64*16];
  const int lofs = half ? 0 : 8;
  const int xofs = half ? 72 : 0;
  for (int ft=tid; ft<1408; ft+=320){
    int ci = ft/22, q = ft - ci*22;
    *(float4*)&rowp[ci*96 + lofs + q*4] =
      *(const float4*)(bufA + (size_t)b*1638400 + (size_t)ci*25600 + (size_t)hw*160 + xofs + q*4);
  }
  for (int idx=tid; idx<512; idx+=320){
    int ci = idx>>3, j = idx&7;
    rowp[ci*96 + (half ? 88+j : j)] = 0.f;
  }
  __syncthreads();
  if (tid < 256){
    const int co = tid >> 2, wvl0 = (tid & 3)*4;
    const int a0 = 2 + wvl0*5;
    float acc[4];
    #pragma unroll
    for (int j=0;j<4;j++) acc[j]=0.f;
    const float* wp0 = we1 + (size_t)co*960;
    for (int ci=0; ci<64; ci++){
      float fl[32];
      const float* rp = &rowp[ci*96 + a0];
      #pragma unroll
      for (int m=0;m<16;m++) *(float2*)&fl[2*m] = *(const float2*)&rp[2*m];
      const float* wp = wp0 + ci*15;
      #pragma unroll
      for (int t=0;t<15;t++){
        float wt = wp[t];
        #pragma unroll
        for (int j=0;j<4;j++) acc[j] += fl[1 + j*5 + t]*wt;
      }
    }
    #pragma unroll
    for (int j=0;j<4;j++) y1s[co*16 + wvl0 + j] = lrelu(acc[j]);
  }
  __syncthreads();
  {
    const int oc = tid, kk = oc >> 6, c = oc & 63;
    float a2[16];
    #pragma unroll
    for (int wv2=0;wv2<16;wv2++) a2[wv2]=0.f;
    const float* wp = we2 + (size_t)oc*64;
    for (int ci=0; ci<64; ci++){
      float wt = wp[ci];
      const float* yp = &y1s[ci*16];
      #pragma unroll
      for (int wv2=0; wv2<16; wv2++) a2[wv2] += yp[wv2]*wt;
    }
    float* y2s = rowp;
    #pragma unroll
    for (int wv2=0; wv2<16; wv2++) y2s[c*84 + wv2*5 + kk] = lrelu(a2[wv2]);
  }
  __syncthreads();
  {
    const float* y2s = rowp;
    for (int k=0;k<4;k++){
      int f = (tid + k*320)*4;
      int c = f/80, rr = f - c*80;
      *(float4*)(out + (size_t)(b*64+c)*25600 + (size_t)hw*160 + half*80 + rr)
        = *(const float4*)&y2s[c*84+rr];
    }
  }
}

// ---------------- permV (unchanged) ----------------------------------------
__global__ __launch_bounds__(256) void k_permV(const float* __restrict__ tmp, float* __restrict__ dst){
  const int bc = blockIdx.x;
  const int ti = blockIdx.y / 5, tj = blockIdx.y % 5;
  const int hw0 = ti*32, r0 = tj*32;
  const int lx = threadIdx.x & 31, ly = threadIdx.x >> 5;
  __shared__ float tile[32][33];
  const float* in = tmp + (size_t)bc*25600;
  float* outp = dst + (size_t)bc*25600;
  for (int yy=ly; yy<32; yy+=8)
    tile[yy][lx] = in[(size_t)(hw0+yy)*160 + r0 + lx];
  __syncthreads();
  for (int yy=ly; yy<32; yy+=8)
    outp[(size_t)(r0+yy)*160 + hw0 + lx] = tile[lx][yy];
}

// ---------------- permM (unchanged) ----------------------------------------
__global__ __launch_bounds__(256) void k_permM(const float* __restrict__ A, float* __restrict__ dst){
  const int bc = blockIdx.x >> 5, hh = blockIdx.x & 31;
  const int tid = threadIdx.x;
  __shared__ float rows[5*160];
  const float* in = A + (size_t)bc*25600;
  if (tid < 200){
    int ai = tid/40, q = (tid - ai*40)*4;
    *(float4*)&rows[ai*160 + q] = *(const float4*)(in + (size_t)(ai*32+hh)*160 + q);
  }
  __syncthreads();
  float* outp = dst + (size_t)bc*25600 + (size_t)hh*800;
  for (int t=tid; t<800; t+=256){
    int ww = t/25, r2 = t - ww*25, ai = r2/5, aj = r2 - ai*5;
    outp[t] = rows[ai*160 + aj*32 + ww];
  }
}

// ---------------- k_red (unchanged) ----------------------------------------
__global__ __launch_bounds__(256) void k_red(const float* __restrict__ b0, const float* __restrict__ b1,
                                             const float* __restrict__ b2, const float* __restrict__ b3,
                                             float* __restrict__ part){
  const int b = blockIdx.y, blk = blockIdx.x;
  const int tid = threadIdx.x;
  const size_t off = (size_t)b*1638400 + (size_t)blk*25600;
  float s0=0,s1=0,s2=0,s3=0;
  float p00=0,p01=0,p02=0,p03=0,p11=0,p12=0,p13=0,p22=0,p23=0,p33=0;
  for (int it=0; it<25; it++){
    size_t m = off + it*1024 + tid*4;
    float4 x0 = *(const float4*)(b0+m);
    float4 x1 = *(const float4*)(b1+m);
    float4 x2 = *(const float4*)(b2+m);
    float4 x3 = *(const float4*)(b3+m);
    s0 += (x0.x+x0.y)+(x0.z+x0.w);
    s1 += (x1.x+x1.y)+(x1.z+x1.w);
    s2 += (x2.x+x2.y)+(x2.z+x2.w);
    s3 += (x3.x+x3.y)+(x3.z+x3.w);
    p00 += x0.x*x0.x+x0.y*x0.y+x0.z*x0.z+x0.w*x0.w;
    p01 += x0.x*x1.x+x0.y*x1.y+x0.z*x1.z+x0.w*x1.w;
    p02 += x0.x*x2.x+x0.y*x2.y+x0.z*x2.z+x0.w*x2.w;
    p03 += x0.x*x3.x+x0.y*x3.y+x0.z*x3.z+x0.w*x3.w;
    p11 += x1.x*x1.x+x1.y*x1.y+x1.z*x1.z+x1.w*x1.w;
    p12 += x1.x*x2.x+x1.y*x2.y+x1.z*x2.z+x1.w*x2.w;
    p13 += x1.x*x3.x+x1.y*x3.y+x1.z*x3.z+x1.w*x3.w;
    p22 += x2.x*x2.x+x2.y*x2.y+x2.z*x2.z+x2.w*x2.w;
    p23 += x2.x*x3.x+x2.y*x3.y+x2.z*x3.z+x2.w*x3.w;
    p33 += x3.x*x3.x+x3.y*x3.y+x3.z*x3.z+x3.w*x3.w;
  }
  float vals[14] = {s0,s1,s2,s3,p00,p01,p02,p03,p11,p12,p13,p22,p23,p33};
  __shared__ float red[4][14];
  int lane = tid & 63, wv = tid >> 6;
  #pragma unroll
  for (int j=0;j<14;j++){
    float v = vals[j];
    #pragma unroll
    for (int o=32;o>0;o>>=1) v += __shfl_down(v,o,64);
    if (lane==0) red[wv][j]=v;
  }
  __syncthreads();
  if (tid<14) part[((size_t)b*64+blk)*16 + tid] = red[0][tid]+red[1][tid]+red[2][tid]+red[3][tid];
}

// ---- k_attW (unchanged) ---------------------------------------------------
__global__ __launch_bounds__(256) void k_attW(const float* __restrict__ part,
        const float* __restrict__ alpha, const float* __restrict__ gamma, const float* __restrict__ beta,
        int iblk, const float* __restrict__ wf1, float* __restrict__ Weff){
  const int b = blockIdx.x, tid = threadIdx.x;
  __shared__ float st[14];
  __shared__ float att[16];
  if (tid<14){
    float t=0;
    for (int blk=0;blk<64;blk++) t += part[((size_t)b*64+blk)*16 + tid];
    st[tid]=t;
  }
  __syncthreads();
  if (tid==0){
    const float M = 1638400.f;
    float s[4] = {st[0],st[1],st[2],st[3]};
    float S[4][4];
    S[0][0]=st[4];  S[0][1]=S[1][0]=st[5];  S[0][2]=S[2][0]=st[6];  S[0][3]=S[3][0]=st[7];
    S[1][1]=st[8];  S[1][2]=S[2][1]=st[9];  S[1][3]=S[3][1]=st[10];
    S[2][2]=st[11]; S[2][3]=S[3][2]=st[12]; S[3][3]=st[13];
    float al=alpha[iblk], ga=gamma[iblk], be=beta[iblk];
    float scale = al/(M-1.f);
    float cov[4][4], ss=0.f;
    for (int n=0;n<4;n++) for (int k=0;k<4;k++){
      float c = (S[n][k] - s[n]*s[k]/M)*scale;
      cov[n][k]=c; ss += c*c;
    }
    float rms = sqrtf(ss/16.f + 1e-5f);
    for (int n=0;n<4;n++) for (int k=0;k<4;k++){
      float g = ga*cov[n][k]/rms + be;
      att[n*4+k] = g/(1.f+expf(-g));
    }
  }
  __syncthreads();
  for (int idx=tid; idx<16384; idx+=256){
    int co=idx>>8, kc=idx&255, k=kc>>6, c=kc&63;
    float v = wf1[co*256+kc];
    #pragma unroll
    for (int n=0;n<4;n++) v += att[n*4+k]*wf1[co*256+n*64+c];
    Weff[(size_t)b*16384+idx] = v;
  }
}

// ---------------- fuse1 (unchanged) ----------------------------------------
__global__ __launch_bounds__(256) void k_fuse1(const float* b0, const float* __restrict__ b1,
                                               const float* __restrict__ b2, const float* __restrict__ b3,
                                               const float* __restrict__ Weff, float* y64){
  const int tile = blockIdx.x, b = blockIdx.y;
  const int px0 = tile*64;
  const int tid = threadIdx.x;
  const int ti = tid >> 4, tj = tid & 15;
  __shared__ float xs[64][68];
  __shared__ float wt[64][68];
  float acc[4][4];
  #pragma unroll
  for (int i=0;i<4;i++)
    #pragma unroll
    for (int j=0;j<4;j++) acc[i][j]=0.f;
  const float* bptr[4] = {b0,b1,b2,b3};
  for (int kb=0; kb<4; kb++){
    const float* xbk = bptr[kb] + (size_t)b*1638400 + px0;
    const float* wb = Weff + (size_t)b*16384 + kb*64;
    __syncthreads();
    for (int idx=tid; idx<4096; idx+=256){
      int kc=idx>>6, px=idx&63;
      xs[kc][px] = xbk[(size_t)kc*25600 + px];
    }
    for (int idx=tid; idx<4096; idx+=256){
      int co=idx>>6, k2=idx&63;
      wt[k2][co] = wb[co*256 + k2];
    }
    __syncthreads();
    for (int k2=0;k2<64;k2++){
      float4 a = *(const float4*)&wt[k2][ti*4];
      float4 v = *(const float4*)&xs[k2][tj*4];
      acc[0][0]+=a.x*v.x; acc[0][1]+=a.x*v.y; acc[0][2]+=a.x*v.z; acc[0][3]+=a.x*v.w;
      acc[1][0]+=a.y*v.x; acc[1][1]+=a.y*v.y; acc[1][2]+=a.y*v.z; acc[1][3]+=a.y*v.w;
      acc[2][0]+=a.z*v.x; acc[2][1]+=a.z*v.y; acc[2][2]+=a.z*v.z; acc[2][3]+=a.z*v.w;
      acc[3][0]+=a.w*v.x; acc[3][1]+=a.w*v.y; acc[3][2]+=a.w*v.z; acc[3][3]+=a.w*v.w;
    }
  }
  #pragma unroll
  for (int i=0;i<4;i++){
    int co = ti*4 + i;
    float4 o = make_float4(lrelu(acc[i][0]), lrelu(acc[i][1]), lrelu(acc[i][2]), lrelu(acc[i][3]));
    *(float4*)(y64 + ((size_t)(b*64+co))*25600 + px0 + tj*4) = o;
  }
}

// ---------------- fuse2: dilated 3x3 (dil 5, pad 5) + residual ------------
// 1-wave blocks (R15 geometry) with global_load_lds staging: slot m -> LDS byte m*16
// (3 chunks of 64/64/16 slots), counted vmcnt(3)/(2) keeps next-ci loads in flight
// across the FMA block; zero s_barrier, zero ds_write.
// grid 6400 = 8xcd x (25tsel x 8cog x 4wv).
template<int FINAL>
__global__ __launch_bounds__(64) void k_fuse2(const float* __restrict__ y64, const float* resid,
                                              const float* __restrict__ w, float* outp){
  const int P = blockIdx.x;
  const int xcd = P & 7, within = P >> 3;
  const int wv = within & 3, cog = (within >> 2) & 7, tsel = within >> 5;  // tsel 0..24
  const int tg = xcd*25 + tsel;                // 0..199
  const int b = tg / 50, tile = tg % 50;
  const int th0 = (tile/5)*16, tw0 = (tile%5)*32;
  const int lane = threadIdx.x;
  __shared__ __align__(16) float wl[2][576];   // 12 row-slots x 48 cols, 2 bufs
  for (int i=lane; i<1152; i+=64) ((float*)wl)[i] = 0.f;
  float acc[2][8];
  #pragma unroll
  for (int k=0;k<2;k++)
    #pragma unroll
    for (int c2=0;c2<8;c2++) acc[k][c2]=0.f;
  const float* src = y64 + (size_t)b*1638400;
  // staging slots m = lane + j*64 (j chunk); slot m -> LDS float m*4 (byte m*16)
  int soff[3];
  bool sok[3];
  #pragma unroll
  for (int j=0;j<3;j++){
    int m = lane + j*64;
    bool act = m < 144;
    int mm = act ? m : 0;
    int srow = mm/12, q = mm - srow*12;
    int dlt = srow + 3*(srow>=2) + (srow>=4) + (srow>=8) + 3*(srow>=10);  // {0,1,5,6,8,9,10,11,13,14,18,19}
    int gh = th0 - 5 + 2*wv + dlt, gw = tw0 - 8 + q*4;
    sok[j] = act && ((unsigned)gh < 160u) && ((unsigned)gw < 160u);
    soff[j] = gh*160 + gw;
  }
  const bool ch2 = __any(sok[2]);              // wave-uniform: chunk 2 issues at all?
  // drain zero-init ds_writes before async loads can land
  asm volatile("s_waitcnt lgkmcnt(0)" ::: "memory");
  // prologue: issue ci=0 into buf0
  {
    float* Q = wl[0];
    if (sok[0]) gl16(src + soff[0], Q);
    if (sok[1]) gl16(src + soff[1], Q + 256);
    if (sok[2]) gl16(src + soff[2], Q + 512);
  }
  const int lrl = (lane >> 5) & 1, c = lane & 31;
  const int t0base = lrl*48 + c + 3;
  for (int ci=0; ci<64; ci++){
    if (ci < 63){
      const float* sN = src + (size_t)(ci+1)*25600;
      float* Q = wl[(ci+1)&1];
      if (sok[0]) gl16(sN + soff[0], Q);
      if (sok[1]) gl16(sN + soff[1], Q + 256);
      if (sok[2]) gl16(sN + soff[2], Q + 512);
      if (ch2) asm volatile("s_waitcnt vmcnt(3)" ::: "memory");
      else     asm volatile("s_waitcnt vmcnt(2)" ::: "memory");
    } else {
      asm volatile("s_waitcnt vmcnt(0)" ::: "memory");
    }
    const float* Pb = wl[ci & 1];
    float t0[9], t1[9];
    {
      const float* pp = &Pb[t0base];
      t0[0]=pp[0];        t0[1]=pp[5];        t0[2]=pp[10];
      t0[3]=pp[2*48];     t0[4]=pp[2*48+5];   t0[5]=pp[2*48+10];
      t0[6]=pp[6*48];     t0[7]=pp[6*48+5];   t0[8]=pp[6*48+10];
      t1[0]=pp[4*48];     t1[1]=pp[4*48+5];   t1[2]=pp[4*48+10];
      t1[3]=pp[8*48];     t1[4]=pp[8*48+5];   t1[5]=pp[8*48+10];
      t1[6]=pp[10*48];    t1[7]=pp[10*48+5];  t1[8]=pp[10*48+10];
    }
    const float* wrow = w + ci*576 + cog*72;   // repacked: 72 contiguous dwords
    #pragma unroll
    for (int co=0;co<8;co++){
      const float* wp = wrow + co*9;
      float w0=wp[0],w1=wp[1],w2=wp[2],w3=wp[3],w4=wp[4],w5=wp[5],w6=wp[6],w7=wp[7],w8=wp[8];
      acc[0][co] += t0[0]*w0+t0[1]*w1+t0[2]*w2+t0[3]*w3+t0[4]*w4
                  + t0[5]*w5+t0[6]*w6+t0[7]*w7+t0[8]*w8;
      acc[1][co] += t1[0]*w0+t1[1]*w1+t1[2]*w2+t1[3]*w3+t1[4]*w4
                  + t1[5]*w5+t1[6]*w6+t1[7]*w7+t1[8]*w8;
    }
  }
  #pragma unroll
  for (int k=0;k<2;k++){
    int h = th0 + 2*wv + lrl + k*8, wq = tw0 + c;
    #pragma unroll
    for (int co=0;co<8;co++){
      int cg = cog*8 + co;
      size_t base = ((size_t)(b*64+cg)*160 + h)*160 + wq;
      outp[base] = acc[k][co] + resid[base];
    }
  }
}

extern "C" void kernel_launch(void* const* d_in, const int* in_sizes, int n_in,
                              void* d_out, int out_size, void* d_ws, size_t ws_size,
                              hipStream_t stream){
  const float* x    = (const float*)d_in[0];
  const float* x1   = (const float*)d_in[1];
  const float* wspa = (const float*)d_in[2];
  const float* wang = (const float*)d_in[3];
  const float* we1  = (const float*)d_in[4];
  const float* we2  = (const float*)d_in[5];
  const float* al   = (const float*)d_in[6];
  const float* ga   = (const float*)d_in[7];
  const float* be   = (const float*)d_in[8];
  const float* wf1  = (const float*)d_in[9];
  const float* wf2  = (const float*)d_in[10];

  char* ws = (char*)d_ws;
  const size_t SLOT = 26214400;
  float* A  = (float*)(ws);          // MacPI buf (in-place residual chain)
  float* Bv = (float*)(ws +   SLOT); // B1 input / branchV / newB1
  float* T1 = (float*)(ws + 2*SLOT); // branchSpa -> y64 in-place
  float* T2 = (float*)(ws + 3*SLOT); // epiV tmp -> branchAng
  float* part = (float*)(ws + 4*SLOT);            // 4*64*16 f32 (16KB)
  float* Weff = (float*)(ws + 4*SLOT + 16384);    // 4*64*256 f32 (256KB)
  float* Wrep = (float*)(ws + 4*SLOT + 16384 + 262144);  // 3*4*36864 f32 (1.7MB)
  float* WspaR = Wrep;
  float* WangR = Wrep + 147456;
  float* Wf2R  = Wrep + 2*147456;
  float* D = (float*)d_out;          // A^T / branchH scratch; final output at the end

  k_wrep<<<1728,256,0,stream>>>(wspa, wang, wf2, Wrep);

  for (int i=0;i<4;i++){
    const float* Asrc  = (i==0) ? x  : (const float*)A;
    const float* B1src = (i==0) ? x1 : (const float*)Bv;
    k_permV<<<dim3(256,25),256,0,stream>>>(Asrc, D);                             // D = Asrc^T
    k_epi<<<1280,320,0,stream>>>(D, we1 + (size_t)i*61440, we2 + (size_t)i*20480, T2);   // epiV (tmp layout)
    k_spa<<<6400,64,0,stream>>>(B1src, WspaR + (size_t)i*36864, T1);
    k_permV<<<dim3(256,25),256,0,stream>>>(T2, Bv);                              // branchV
    k_ang<<<1024,320,0,stream>>>(Asrc, WangR + (size_t)i*36864, T2);
    k_epi<<<1280,320,0,stream>>>(Asrc, we1 + (size_t)i*61440, we2 + (size_t)i*20480, D); // branchH
    k_red<<<dim3(64,4),256,0,stream>>>(T1, T2, D, Bv, part);
    k_attW<<<4,256,0,stream>>>(part, al, ga, be, i, wf1 + (size_t)i*16384, Weff);
    k_fuse1<<<dim3(400,4),256,0,stream>>>(T1, T2, D, Bv, Weff, T1);
    if (i<3){
      k_fuse2<0><<<6400,64,0,stream>>>(T1, Asrc, Wf2R + (size_t)i*36864, A);
      k_permM<<<8192,256,0,stream>>>(A, Bv);
    } else {
      k_fuse2<1><<<6400,64,0,stream>>>(T1, Asrc, Wf2R + (size_t)i*36864, D);
    }
  }
}